// Round 6
// baseline (290.297 us; speedup 1.0000x reference)
//
#include <hip/hip_runtime.h>
#include <hip/hip_bf16.h>

#define N_NODES   50000
#define N_EDGES   600000
#define F         128
#define N_GRAPHS  64
#define N_CLASSES 10
#define NPAD      50048           // multiple of 64
#define NB_SCAN   196             // ceil(50000/256)
#define XCVT_BLOCKS 6250          // N_NODES*F/4/256
#define BM        32              // conv tile rows

typedef __attribute__((ext_vector_type(8))) short bf16x8;
typedef __attribute__((ext_vector_type(4))) float f32x4;

static __device__ __forceinline__ unsigned short f2bf(float f) {
    __hip_bfloat16 h = __float2bfloat16(f);
    return *reinterpret_cast<unsigned short*>(&h);
}
static __device__ __forceinline__ float bf2f(unsigned short u) {
    return __uint_as_float(((unsigned)u) << 16);
}

// ================= CSR build =================
__global__ __launch_bounds__(256) void hist_kernel(
    const int* __restrict__ dst, int* __restrict__ deg)
{
    int e = blockIdx.x * 256 + threadIdx.x;
    if (e >= N_EDGES) return;
    atomicAdd(&deg[dst[e]], 1);
}

__global__ __launch_bounds__(256) void scanA_kernel(
    const int* __restrict__ deg, int* __restrict__ locEx, int* __restrict__ blockSum)
{
    __shared__ int sh[256];
    int t = threadIdx.x;
    int idx = blockIdx.x * 256 + t;
    int v = (idx < N_NODES) ? deg[idx] : 0;
    sh[t] = v;
    __syncthreads();
#pragma unroll
    for (int d = 1; d < 256; d <<= 1) {
        int u = (t >= d) ? sh[t - d] : 0;
        __syncthreads();
        sh[t] += u;
        __syncthreads();
    }
    if (idx < N_NODES) locEx[idx] = sh[t] - v;
    if (t == 255) blockSum[blockIdx.x] = sh[255];
}

// every block scans the 196 block sums in LDS, then adds its base
__global__ __launch_bounds__(256) void scanBC_kernel(
    const int* __restrict__ locEx, const int* __restrict__ blockSum,
    int* __restrict__ off)
{
    __shared__ int sh[256];
    int t = threadIdx.x;
    int v = (t < NB_SCAN) ? blockSum[t] : 0;
    sh[t] = v;
    __syncthreads();
#pragma unroll
    for (int d = 1; d < 256; d <<= 1) {
        int u = (t >= d) ? sh[t - d] : 0;
        __syncthreads();
        sh[t] += u;
        __syncthreads();
    }
    int myVal  = blockSum[blockIdx.x];
    int base   = sh[blockIdx.x] - myVal;
    int idx = blockIdx.x * 256 + t;
    if (idx < N_NODES) off[idx] = locEx[idx] + base;
    if (blockIdx.x == 0 && t == 0) off[N_NODES] = sh[NB_SCAN - 1];
}

__global__ __launch_bounds__(256) void fill_kernel(
    const int* __restrict__ src, const int* __restrict__ dst,
    const int* __restrict__ off, int* __restrict__ cursor,
    int* __restrict__ csr_src)
{
    int e = blockIdx.x * 256 + threadIdx.x;
    if (e >= N_EDGES) return;
    int d = dst[e];
    int slot = atomicAdd(&cursor[d], 1);
    csr_src[off[d] + slot] = src[e];
}

// ================= all fp32->bf16 conversions in ONE dispatch =================
__global__ __launch_bounds__(256) void cvt_all_kernel(
    const float* __restrict__ x,
    const float* __restrict__ W0, const float* __restrict__ W1,
    const float* __restrict__ W2, const float* __restrict__ W3,
    const float* __restrict__ W4, const float* __restrict__ W5,
    unsigned short* __restrict__ Xb, unsigned short* __restrict__ Wb)
{
    int b = blockIdx.x;
    if (b < XCVT_BLOCKS) {
        int i = b * 256 + threadIdx.x;
        float4 v = reinterpret_cast<const float4*>(x)[i];
        ushort4 o;
        o.x = f2bf(v.x); o.y = f2bf(v.y); o.z = f2bf(v.z); o.w = f2bf(v.w);
        reinterpret_cast<ushort4*>(Xb)[i] = o;
    } else {
        const int PER = (F * F / 4) / 256;   // 16
        int bb  = b - XCVT_BLOCKS;
        int mat = bb / PER;
        int i   = (bb % PER) * 256 + threadIdx.x;
        const float* W = (mat == 0) ? W0 : (mat == 1) ? W1 : (mat == 2) ? W2
                       : (mat == 3) ? W3 : (mat == 4) ? W4 : W5;
        float4 v = reinterpret_cast<const float4*>(W)[i];
        ushort4 o;
        o.x = f2bf(v.x); o.y = f2bf(v.y); o.z = f2bf(v.z); o.w = f2bf(v.w);
        reinterpret_cast<ushort4*>(Wb + (size_t)mat * F * F)[i] = o;
    }
}

// ================= fused gather + GraphConv via MFMA =================
// BM=32 rows/block. Phase 1: 8 threads/row, 16 feats each, 2-deep pipelined
// edge loop, fp32 accum -> bf16 LDS (XOR-swizzled). Phase 2: 4 waves 2Mx2N,
// wave tile 16x64: H = [relu](AGG@Wrel^T + b + X@Wroot^T).
template <int RELU>
__global__ __launch_bounds__(256) void conv_fused(
    const unsigned short* __restrict__ Xb,
    const int* __restrict__ off, const int* __restrict__ csr_src,
    const unsigned short* __restrict__ Wrel, const unsigned short* __restrict__ Wroot,
    const float* __restrict__ brel, unsigned short* __restrict__ H)
{
    __shared__ char AsRaw[BM * 256];   // As[32][128] bf16, byte-XOR swizzled rows
    const int t = threadIdx.x;
    const int mBase = blockIdx.x * BM;

    // ---- phase 1: per-row neighbor sum ----
    {
        const int r = t >> 3;            // 0..31
        const int q = t & 7;             // 0..7 -> features q*16 .. q*16+15
        int row = mBase + r;
        float acc[16];
#pragma unroll
        for (int i = 0; i < 16; ++i) acc[i] = 0.f;
        if (row < N_NODES) {
            int s0 = off[row], s1 = off[row + 1];
            const unsigned short* Xq = Xb + (size_t)q * 16;
            if (s0 < s1) {
                int s = csr_src[s0];
                bf16x8 v0 = *reinterpret_cast<const bf16x8*>(Xq + (size_t)s * F);
                bf16x8 v1 = *reinterpret_cast<const bf16x8*>(Xq + (size_t)s * F + 8);
                for (int j = s0 + 1; j < s1; ++j) {
                    int sn = csr_src[j];
                    bf16x8 u0 = *reinterpret_cast<const bf16x8*>(Xq + (size_t)sn * F);
                    bf16x8 u1 = *reinterpret_cast<const bf16x8*>(Xq + (size_t)sn * F + 8);
#pragma unroll
                    for (int e = 0; e < 8; ++e) {
                        acc[e]     += bf2f((unsigned short)v0[e]);
                        acc[8 + e] += bf2f((unsigned short)v1[e]);
                    }
                    v0 = u0; v1 = u1;
                }
#pragma unroll
                for (int e = 0; e < 8; ++e) {
                    acc[e]     += bf2f((unsigned short)v0[e]);
                    acc[8 + e] += bf2f((unsigned short)v1[e]);
                }
            }
        }
        bf16x8 o0, o1;
#pragma unroll
        for (int e = 0; e < 8; ++e) {
            o0[e] = (short)f2bf(acc[e]);
            o1[e] = (short)f2bf(acc[8 + e]);
        }
        int sw = (r & 7) << 4;
        *reinterpret_cast<bf16x8*>(AsRaw + r * 256 + ((q * 32)      ^ sw)) = o0;
        *reinterpret_cast<bf16x8*>(AsRaw + r * 256 + ((q * 32 + 16) ^ sw)) = o1;
    }
    __syncthreads();

    // ---- phase 2: MFMA, 4 waves in 2Mx2N, wave tile 16x64 ----
    const int wave = t >> 6;
    const int lane = t & 63;
    const int wm = wave >> 1, wn = wave & 1;
    const int m0l = wm * 16;
    const int n0  = wn * 64;
    const int lrow = lane & 15;
    const int lk8  = (lane >> 4) << 3;
    const int arow = m0l + lrow;

    f32x4 acc2[4];
#pragma unroll
    for (int ni = 0; ni < 4; ++ni) acc2[ni] = (f32x4){0.f, 0.f, 0.f, 0.f};

#pragma unroll
    for (int p = 0; p < 2; ++p) {
        const unsigned short* W = p ? Wroot : Wrel;
#pragma unroll
        for (int ks = 0; ks < 4; ++ks) {
            int k0 = ks * 32 + lk8;
            bf16x8 a, b[4];
            if (p == 0) {
                int bytecol = (k0 * 2) ^ ((arow & 7) << 4);
                a = *reinterpret_cast<const bf16x8*>(AsRaw + arow * 256 + bytecol);
            } else {
                a = *reinterpret_cast<const bf16x8*>(
                    Xb + (size_t)(mBase + arow) * F + k0);
            }
#pragma unroll
            for (int ni = 0; ni < 4; ++ni)
                b[ni] = *reinterpret_cast<const bf16x8*>(
                    W + (size_t)(n0 + ni * 16 + lrow) * F + k0);
#pragma unroll
            for (int ni = 0; ni < 4; ++ni)
                acc2[ni] = __builtin_amdgcn_mfma_f32_16x16x32_bf16(
                    a, b[ni], acc2[ni], 0, 0, 0);
        }
    }

    const int r0 = (lane >> 4) << 2;   // C/D: row = (lane>>4)*4 + reg
#pragma unroll
    for (int ni = 0; ni < 4; ++ni) {
        int col = n0 + ni * 16 + lrow;
        float bb = brel[col];
#pragma unroll
        for (int r = 0; r < 4; ++r) {
            int row = mBase + m0l + r0 + r;
            if (row < N_NODES) {
                float v = acc2[ni][r] + bb;
                if (RELU) v = fmaxf(v, 0.f);
                H[(size_t)row * F + col] = f2bf(v);
            }
        }
    }
}

// ================= mean pool (bf16 in, fp32 out) =================
__global__ __launch_bounds__(256) void pool_kernel(
    const unsigned short* __restrict__ H, const int* __restrict__ batch,
    float* __restrict__ G)
{
    int g = blockIdx.x;
    int lo = 0, hi = N_NODES;
    while (lo < hi) { int m = (lo + hi) >> 1; if (batch[m] < g) lo = m + 1; else hi = m; }
    int start = lo;
    hi = N_NODES;
    while (lo < hi) { int m = (lo + hi) >> 1; if (batch[m] < g + 1) lo = m + 1; else hi = m; }
    int end = lo;

    int l8 = (threadIdx.x & 15) << 3;
    int rg = threadIdx.x >> 4;
    float acc[8] = {0.f, 0.f, 0.f, 0.f, 0.f, 0.f, 0.f, 0.f};
    for (int i = start + rg; i < end; i += 16) {
        bf16x8 v = *reinterpret_cast<const bf16x8*>(H + (size_t)i * F + l8);
#pragma unroll
        for (int r = 0; r < 8; ++r) acc[r] += bf2f((unsigned short)v[r]);
    }
    __shared__ float sh[16][F];
#pragma unroll
    for (int r = 0; r < 8; ++r) sh[rg][l8 + r] = acc[r];
    __syncthreads();
    if (threadIdx.x < F) {
        int f = threadIdx.x;
        float s = 0.f;
#pragma unroll
        for (int k = 0; k < 16; ++k) s += sh[k][f];
        float cnt = (float)(end - start);
        G[g * F + f] = s / fmaxf(cnt, 1.f);
    }
}

// ================= head =================
__global__ __launch_bounds__(640) void head_kernel(
    const float* __restrict__ G, const float* __restrict__ Wl,
    const float* __restrict__ bl, float* __restrict__ out)
{
    int t = threadIdx.x;
    int g = t / N_CLASSES;
    int c = t % N_CLASSES;
    float s = bl[c];
#pragma unroll 8
    for (int k = 0; k < F; ++k) s += G[g * F + k] * Wl[c * F + k];
    out[t] = s;
}

extern "C" void kernel_launch(void* const* d_in, const int* in_sizes, int n_in,
                              void* d_out, int out_size, void* d_ws, size_t ws_size,
                              hipStream_t stream)
{
    const float* x     = (const float*)d_in[0];
    const int*   edge  = (const int*)d_in[1];
    const int*   src   = edge;
    const int*   dst   = edge + N_EDGES;
    const int*   batch = (const int*)d_in[2];
    const float* W1r = (const float*)d_in[3];
    const float* b1  = (const float*)d_in[4];
    const float* W1o = (const float*)d_in[5];
    const float* W2r = (const float*)d_in[6];
    const float* b2  = (const float*)d_in[7];
    const float* W2o = (const float*)d_in[8];
    const float* W3r = (const float*)d_in[9];
    const float* b3  = (const float*)d_in[10];
    const float* W3o = (const float*)d_in[11];
    const float* Wl  = (const float*)d_in[12];
    const float* bl  = (const float*)d_in[13];
    float* out = (float*)d_out;

    char* ws = (char*)d_ws;
    const size_t fb = (size_t)NPAD * F * sizeof(unsigned short);   // 12.8 MB
    unsigned short* Xb  = (unsigned short*)ws;
    unsigned short* H1b = (unsigned short*)(ws + fb);
    unsigned short* H2b = (unsigned short*)(ws + 2 * fb);
    char* p = ws + 3 * fb;
    unsigned short* Wb = (unsigned short*)p;   // 6 contiguous FxF panels
    p += (size_t)6 * F * F * sizeof(unsigned short);
    float* G = (float*)p;                p += (size_t)N_GRAPHS * F * sizeof(float);
    int* deg     = (int*)p;              p += (size_t)N_NODES * sizeof(int);
    int* cursor  = (int*)p;              p += (size_t)N_NODES * sizeof(int);  // contiguous w/ deg
    int* off     = (int*)p;              p += (size_t)(N_NODES + 1) * sizeof(int);
    int* locEx   = (int*)p;              p += (size_t)N_NODES * sizeof(int);
    int* blockSum= (int*)p;              p += (size_t)256 * sizeof(int);
    int* csr_src = (int*)p;

    const int edgeBlocks = (N_EDGES + 255) / 256;            // 2344
    const int convBlocks = NPAD / BM;                        // 1564
    const int cvtBlocks  = XCVT_BLOCKS + 6 * (F * F / 4) / 256;  // 6346

    // ---- conversions (one dispatch) ----
    cvt_all_kernel<<<cvtBlocks, 256, 0, stream>>>(x, W1r, W1o, W2r, W2o, W3r, W3o, Xb, Wb);

    // ---- CSR build ----
    hipMemsetAsync(deg, 0, (size_t)2 * N_NODES * sizeof(int), stream);  // deg + cursor
    hist_kernel<<<edgeBlocks, 256, 0, stream>>>(dst, deg);
    scanA_kernel<<<NB_SCAN, 256, 0, stream>>>(deg, locEx, blockSum);
    scanBC_kernel<<<NB_SCAN, 256, 0, stream>>>(locEx, blockSum, off);
    fill_kernel<<<edgeBlocks, 256, 0, stream>>>(src, dst, off, cursor, csr_src);

    // ---- 3 fused layers ----
    conv_fused<1><<<convBlocks, 256, 0, stream>>>(Xb,  off, csr_src, Wb + 0 * F * F, Wb + 1 * F * F, b1, H1b);
    conv_fused<1><<<convBlocks, 256, 0, stream>>>(H1b, off, csr_src, Wb + 2 * F * F, Wb + 3 * F * F, b2, H2b);
    conv_fused<0><<<convBlocks, 256, 0, stream>>>(H2b, off, csr_src, Wb + 4 * F * F, Wb + 5 * F * F, b3, H1b);

    // ---- pool + head ----
    pool_kernel<<<N_GRAPHS, 256, 0, stream>>>(H1b, batch, G);
    head_kernel<<<1, 640, 0, stream>>>(G, Wl, bl, out);
}

// Round 7
// 266.196 us; speedup vs baseline: 1.0905x; 1.0905x over previous
//
#include <hip/hip_runtime.h>
#include <hip/hip_bf16.h>

#define N_NODES   50000
#define N_EDGES   600000
#define F         128
#define N_GRAPHS  64
#define N_CLASSES 10
#define NPAD      50048           // multiple of 64
#define NB_SCAN   196             // ceil(50000/256)
#define XCVT_BLOCKS 6250          // N_NODES*F/4/256
#define PE        ((size_t)NPAD * 32)   // elements per feature plane (32 feats/plane)

typedef __attribute__((ext_vector_type(8))) short bf16x8;
typedef __attribute__((ext_vector_type(4))) float f32x4;

static __device__ __forceinline__ unsigned short f2bf(float f) {
    __hip_bfloat16 h = __float2bfloat16(f);
    return *reinterpret_cast<unsigned short*>(&h);
}
static __device__ __forceinline__ float bf2f(unsigned short u) {
    return __uint_as_float(((unsigned)u) << 16);
}

// ================= CSR build =================
__global__ __launch_bounds__(256) void hist_kernel(
    const int* __restrict__ dst, int* __restrict__ deg)
{
    int e = blockIdx.x * 256 + threadIdx.x;
    if (e >= N_EDGES) return;
    atomicAdd(&deg[dst[e]], 1);
}

__global__ __launch_bounds__(256) void scanA_kernel(
    const int* __restrict__ deg, int* __restrict__ locEx, int* __restrict__ blockSum)
{
    __shared__ int sh[256];
    int t = threadIdx.x;
    int idx = blockIdx.x * 256 + t;
    int v = (idx < N_NODES) ? deg[idx] : 0;
    sh[t] = v;
    __syncthreads();
#pragma unroll
    for (int d = 1; d < 256; d <<= 1) {
        int u = (t >= d) ? sh[t - d] : 0;
        __syncthreads();
        sh[t] += u;
        __syncthreads();
    }
    if (idx < N_NODES) locEx[idx] = sh[t] - v;
    if (t == 255) blockSum[blockIdx.x] = sh[255];
}

__global__ __launch_bounds__(256) void scanBC_kernel(
    const int* __restrict__ locEx, const int* __restrict__ blockSum,
    int* __restrict__ off)
{
    __shared__ int sh[256];
    int t = threadIdx.x;
    int v = (t < NB_SCAN) ? blockSum[t] : 0;
    sh[t] = v;
    __syncthreads();
#pragma unroll
    for (int d = 1; d < 256; d <<= 1) {
        int u = (t >= d) ? sh[t - d] : 0;
        __syncthreads();
        sh[t] += u;
        __syncthreads();
    }
    int myVal  = blockSum[blockIdx.x];
    int base   = sh[blockIdx.x] - myVal;
    int idx = blockIdx.x * 256 + t;
    if (idx < N_NODES) off[idx] = locEx[idx] + base;
    if (blockIdx.x == 0 && t == 0) off[N_NODES] = sh[NB_SCAN - 1];
}

__global__ __launch_bounds__(256) void fill_kernel(
    const int* __restrict__ src, const int* __restrict__ dst,
    const int* __restrict__ off, int* __restrict__ cursor,
    int* __restrict__ csr_src)
{
    int e = blockIdx.x * 256 + threadIdx.x;
    if (e >= N_EDGES) return;
    int d = dst[e];
    int slot = atomicAdd(&cursor[d], 1);
    csr_src[off[d] + slot] = src[e];
}

// ================= fp32 -> bf16 conversions (X to sliced layout) =================
__global__ __launch_bounds__(256) void cvt_all_kernel(
    const float* __restrict__ x,
    const float* __restrict__ W0, const float* __restrict__ W1,
    const float* __restrict__ W2, const float* __restrict__ W3,
    const float* __restrict__ W4, const float* __restrict__ W5,
    unsigned short* __restrict__ Xs, unsigned short* __restrict__ Wb)
{
    int b = blockIdx.x;
    if (b < XCVT_BLOCKS) {
        int i = b * 256 + threadIdx.x;          // float4 index
        int n  = i >> 5;                        // node
        int f4 = (i & 31) << 2;                 // feature base (mult of 4)
        float4 v = reinterpret_cast<const float4*>(x)[i];
        ushort4 o;
        o.x = f2bf(v.x); o.y = f2bf(v.y); o.z = f2bf(v.z); o.w = f2bf(v.w);
        *reinterpret_cast<ushort4*>(Xs + (size_t)(f4 >> 5) * PE + (size_t)n * 32 + (f4 & 31)) = o;
    } else {
        const int PER = (F * F / 4) / 256;   // 16
        int bb  = b - XCVT_BLOCKS;
        int mat = bb / PER;
        int i   = (bb % PER) * 256 + threadIdx.x;
        const float* W = (mat == 0) ? W0 : (mat == 1) ? W1 : (mat == 2) ? W2
                       : (mat == 3) ? W3 : (mat == 4) ? W4 : W5;
        float4 v = reinterpret_cast<const float4*>(W)[i];
        ushort4 o;
        o.x = f2bf(v.x); o.y = f2bf(v.y); o.z = f2bf(v.z); o.w = f2bf(v.w);
        reinterpret_cast<ushort4*>(Wb + (size_t)mat * F * F)[i] = o;
    }
}

// ================= XCD-pinned sliced gather =================
// block -> xcd = b&7; slice = xcd&3 (each slice owned by 2 XCDs); 64 rows/block,
// 4 threads/row, 8 feats (16B) per thread within the slice's 32-feat plane.
// Each XCD only ever reads ONE ~3.2MB plane -> L2-resident.
__global__ __launch_bounds__(256) void gather_sliced(
    const unsigned short* __restrict__ Xs, const int* __restrict__ off,
    const int* __restrict__ csr_src, unsigned short* __restrict__ AGGs)
{
    const int b    = blockIdx.x;
    const int xcd  = b & 7;
    const int s    = xcd & 3;
    const int tile = ((b >> 3) << 1) | (xcd >> 2);
    const int r    = threadIdx.x >> 2;        // 0..63
    const int fq   = threadIdx.x & 3;
    const int row  = tile * 64 + r;

    const unsigned short* Xp = Xs + (size_t)s * PE + fq * 8;
    float acc[8] = {0.f, 0.f, 0.f, 0.f, 0.f, 0.f, 0.f, 0.f};

    if (row < N_NODES) {
        int j0 = off[row], j1 = off[row + 1];
        if (j0 < j1) {
            int sc = csr_src[j0];
            bf16x8 v = *reinterpret_cast<const bf16x8*>(Xp + (size_t)sc * 32);
            for (int j = j0 + 1; j < j1; ++j) {
                int sn = csr_src[j];
                bf16x8 u = *reinterpret_cast<const bf16x8*>(Xp + (size_t)sn * 32);
#pragma unroll
                for (int e = 0; e < 8; ++e) acc[e] += bf2f((unsigned short)v[e]);
                v = u;
            }
#pragma unroll
            for (int e = 0; e < 8; ++e) acc[e] += bf2f((unsigned short)v[e]);
        }
    }
    bf16x8 o;
#pragma unroll
    for (int e = 0; e < 8; ++e) o[e] = (short)f2bf(acc[e]);
    *reinterpret_cast<bf16x8*>(AGGs + (size_t)s * PE + (size_t)row * 32 + fq * 8) = o;
}

// ================= GraphConv via MFMA (direct-global, sliced operands) =================
// H = [relu](AGG@Wrel^T + b + X@Wroot^T). 4 waves 2x2, wave tile 32x64.
template <int RELU>
__global__ __launch_bounds__(256) void conv_mfma(
    const unsigned short* __restrict__ AGGs, const unsigned short* __restrict__ Xs,
    const unsigned short* __restrict__ Wrel, const unsigned short* __restrict__ Wroot,
    const float* __restrict__ brel, unsigned short* __restrict__ Hs)
{
    const int t    = threadIdx.x;
    const int wave = t >> 6;
    const int lane = t & 63;
    const int wm = wave >> 1, wn = wave & 1;
    const int m0 = blockIdx.x * 64 + wm * 32;
    const int n0 = wn * 64;
    const int lrow = lane & 15;
    const int lk8  = (lane >> 4) << 3;   // 0,8,16,24

    f32x4 acc[2][4];
#pragma unroll
    for (int mi = 0; mi < 2; ++mi)
#pragma unroll
        for (int ni = 0; ni < 4; ++ni)
            acc[mi][ni] = (f32x4){0.f, 0.f, 0.f, 0.f};

#pragma unroll
    for (int p = 0; p < 2; ++p) {
        const unsigned short* A = p ? Xs : AGGs;
        const unsigned short* W = p ? Wroot : Wrel;
#pragma unroll
        for (int ks = 0; ks < 4; ++ks) {
            bf16x8 a[2], b[4];
#pragma unroll
            for (int mi = 0; mi < 2; ++mi)
                a[mi] = *reinterpret_cast<const bf16x8*>(
                    A + (size_t)ks * PE + (size_t)(m0 + mi * 16 + lrow) * 32 + lk8);
#pragma unroll
            for (int ni = 0; ni < 4; ++ni)
                b[ni] = *reinterpret_cast<const bf16x8*>(
                    W + (size_t)(n0 + ni * 16 + lrow) * F + ks * 32 + lk8);
#pragma unroll
            for (int mi = 0; mi < 2; ++mi)
#pragma unroll
                for (int ni = 0; ni < 4; ++ni)
                    acc[mi][ni] = __builtin_amdgcn_mfma_f32_16x16x32_bf16(
                        a[mi], b[ni], acc[mi][ni], 0, 0, 0);
        }
    }

    const int r0 = (lane >> 4) << 2;   // C/D: row = (lane>>4)*4 + reg
#pragma unroll
    for (int ni = 0; ni < 4; ++ni) {
        int col = n0 + ni * 16 + lrow;
        float bb = brel[col];
        size_t cplane = (size_t)(col >> 5) * PE + (col & 31);
#pragma unroll
        for (int mi = 0; mi < 2; ++mi) {
#pragma unroll
            for (int r = 0; r < 4; ++r) {
                int row = m0 + mi * 16 + r0 + r;
                if (row < N_NODES) {
                    float v = acc[mi][ni][r] + bb;
                    if (RELU) v = fmaxf(v, 0.f);
                    Hs[cplane + (size_t)row * 32] = f2bf(v);
                }
            }
        }
    }
}

// ================= mean pool (sliced bf16 in, fp32 out) =================
__global__ __launch_bounds__(256) void pool_kernel(
    const unsigned short* __restrict__ Hs, const int* __restrict__ batch,
    float* __restrict__ G)
{
    int g = blockIdx.x;
    int lo = 0, hi = N_NODES;
    while (lo < hi) { int m = (lo + hi) >> 1; if (batch[m] < g) lo = m + 1; else hi = m; }
    int start = lo;
    hi = N_NODES;
    while (lo < hi) { int m = (lo + hi) >> 1; if (batch[m] < g + 1) lo = m + 1; else hi = m; }
    int end = lo;

    int l8 = (threadIdx.x & 15) << 3;           // feature base, mult of 8
    int rg = threadIdx.x >> 4;
    const unsigned short* Hp = Hs + (size_t)(l8 >> 5) * PE + (l8 & 31);
    float acc[8] = {0.f, 0.f, 0.f, 0.f, 0.f, 0.f, 0.f, 0.f};
    for (int i = start + rg; i < end; i += 16) {
        bf16x8 v = *reinterpret_cast<const bf16x8*>(Hp + (size_t)i * 32);
#pragma unroll
        for (int r = 0; r < 8; ++r) acc[r] += bf2f((unsigned short)v[r]);
    }
    __shared__ float sh[16][F];
#pragma unroll
    for (int r = 0; r < 8; ++r) sh[rg][l8 + r] = acc[r];
    __syncthreads();
    if (threadIdx.x < F) {
        int f = threadIdx.x;
        float s = 0.f;
#pragma unroll
        for (int k = 0; k < 16; ++k) s += sh[k][f];
        float cnt = (float)(end - start);
        G[g * F + f] = s / fmaxf(cnt, 1.f);
    }
}

// ================= head =================
__global__ __launch_bounds__(640) void head_kernel(
    const float* __restrict__ G, const float* __restrict__ Wl,
    const float* __restrict__ bl, float* __restrict__ out)
{
    int t = threadIdx.x;
    int g = t / N_CLASSES;
    int c = t % N_CLASSES;
    float s = bl[c];
#pragma unroll 8
    for (int k = 0; k < F; ++k) s += G[g * F + k] * Wl[c * F + k];
    out[t] = s;
}

extern "C" void kernel_launch(void* const* d_in, const int* in_sizes, int n_in,
                              void* d_out, int out_size, void* d_ws, size_t ws_size,
                              hipStream_t stream)
{
    const float* x     = (const float*)d_in[0];
    const int*   edge  = (const int*)d_in[1];
    const int*   src   = edge;
    const int*   dst   = edge + N_EDGES;
    const int*   batch = (const int*)d_in[2];
    const float* W1r = (const float*)d_in[3];
    const float* b1  = (const float*)d_in[4];
    const float* W1o = (const float*)d_in[5];
    const float* W2r = (const float*)d_in[6];
    const float* b2  = (const float*)d_in[7];
    const float* W2o = (const float*)d_in[8];
    const float* W3r = (const float*)d_in[9];
    const float* b3  = (const float*)d_in[10];
    const float* W3o = (const float*)d_in[11];
    const float* Wl  = (const float*)d_in[12];
    const float* bl  = (const float*)d_in[13];
    float* out = (float*)d_out;

    char* ws = (char*)d_ws;
    const size_t fb = (size_t)NPAD * F * sizeof(unsigned short);   // 12.8 MB (4 planes)
    unsigned short* Xs   = (unsigned short*)ws;
    unsigned short* AGGs = (unsigned short*)(ws + fb);
    unsigned short* H1s  = (unsigned short*)(ws + 2 * fb);
    unsigned short* H2s  = (unsigned short*)(ws + 3 * fb);
    char* p = ws + 4 * fb;
    unsigned short* Wb = (unsigned short*)p;   // 6 contiguous FxF panels (row-major)
    p += (size_t)6 * F * F * sizeof(unsigned short);
    float* G = (float*)p;                p += (size_t)N_GRAPHS * F * sizeof(float);
    int* deg     = (int*)p;              p += (size_t)N_NODES * sizeof(int);
    int* cursor  = (int*)p;              p += (size_t)N_NODES * sizeof(int);  // contiguous w/ deg
    int* off     = (int*)p;              p += (size_t)(N_NODES + 1) * sizeof(int);
    int* locEx   = (int*)p;              p += (size_t)N_NODES * sizeof(int);
    int* blockSum= (int*)p;              p += (size_t)256 * sizeof(int);
    int* csr_src = (int*)p;

    const int edgeBlocks   = (N_EDGES + 255) / 256;              // 2344
    const int convBlocks   = NPAD / 64;                          // 782
    const int gatherBlocks = (NPAD / 64 / 2) * 8;                // 391*8 = 3128
    const int cvtBlocks    = XCVT_BLOCKS + 6 * (F * F / 4) / 256;

    // ---- conversions ----
    cvt_all_kernel<<<cvtBlocks, 256, 0, stream>>>(x, W1r, W1o, W2r, W2o, W3r, W3o, Xs, Wb);

    // ---- CSR build ----
    hipMemsetAsync(deg, 0, (size_t)2 * N_NODES * sizeof(int), stream);  // deg + cursor
    hist_kernel<<<edgeBlocks, 256, 0, stream>>>(dst, deg);
    scanA_kernel<<<NB_SCAN, 256, 0, stream>>>(deg, locEx, blockSum);
    scanBC_kernel<<<NB_SCAN, 256, 0, stream>>>(locEx, blockSum, off);
    fill_kernel<<<edgeBlocks, 256, 0, stream>>>(src, dst, off, cursor, csr_src);

    // ---- 3 layers: sliced gather + streaming MFMA conv ----
    gather_sliced<<<gatherBlocks, 256, 0, stream>>>(Xs,  off, csr_src, AGGs);
    conv_mfma<1><<<convBlocks, 256, 0, stream>>>(AGGs, Xs,  Wb + 0 * F * F, Wb + 1 * F * F, b1, H1s);
    gather_sliced<<<gatherBlocks, 256, 0, stream>>>(H1s, off, csr_src, AGGs);
    conv_mfma<1><<<convBlocks, 256, 0, stream>>>(AGGs, H1s, Wb + 2 * F * F, Wb + 3 * F * F, b2, H2s);
    gather_sliced<<<gatherBlocks, 256, 0, stream>>>(H2s, off, csr_src, AGGs);
    conv_mfma<0><<<convBlocks, 256, 0, stream>>>(AGGs, H2s, Wb + 4 * F * F, Wb + 5 * F * F, b3, H1s);

    // ---- pool + head ----
    pool_kernel<<<N_GRAPHS, 256, 0, stream>>>(H1s, batch, G);
    head_kernel<<<1, 640, 0, stream>>>(G, Wl, bl, out);
}